// Round 2
// baseline (2935.995 us; speedup 1.0000x reference)
//
#include <hip/hip_runtime.h>
#include <stdint.h>

#define B_ 256
#define S_ 512
#define H_ 512

// Per-wg LDS (bytes):
//   [0,16384)        imp_lds : W_imp B-tile, replicated across all 16 cols
//   [16384,49216)    xm_lds  : packed (x*(1-m), m) bf16 pairs, [16 rows][513 dwords]
//   [49216,81984)    aP      : packed A (h bf16) [2 parity][16 rows][512 cols], XOR-swizzled
// 81984 > 163840/2 => exactly 1 wg/CU (256 wgs on 256 CUs).
#define XM_STRIDE 513
#define LDS_BYTES 81984

typedef __attribute__((ext_vector_type(4))) float f32x4;
typedef __attribute__((ext_vector_type(4))) int   i32x4;
typedef __attribute__((ext_vector_type(8))) short s16x8;

__device__ __forceinline__ short f2bf(float f) {
    union { float f; uint32_t u; } c; c.f = f;
    uint32_t u = c.u;
    u += 0x7fffu + ((u >> 16) & 1u);   // round-to-nearest-even
    return (short)(u >> 16);
}
__device__ __forceinline__ float bflo(uint32_t u) { return __builtin_bit_cast(float, u << 16); }
__device__ __forceinline__ float bfhi(uint32_t u) { return __builtin_bit_cast(float, u & 0xffff0000u); }
__device__ __forceinline__ float sig_(float x)  { return 1.0f / (1.0f + __expf(-x)); }
__device__ __forceinline__ float tanh_(float x) { return 1.0f - 2.0f / (1.0f + __expf(2.0f * x)); }

// pack low16 of (lo,hi) -> dword [lo.l16 | hi.l16<<16]
__device__ __forceinline__ uint32_t pklo(uint32_t hi, uint32_t lo) {
    return __builtin_amdgcn_perm(hi, lo, 0x05040100u);
}

// Issue this wave's 4 owned chunks (8 dwordx4 = 32 tagged dwords), NO wait.
// sc0 sc1 = read at the LLC (cross-XCD coherence point). Re-issued on retry.
// "=&v" early-clobber: global_load writes dest only at data RETURN, so without
// it the allocator may alias an output with the address reg -> wild reads.
__device__ __forceinline__ void load_a8_issue(const void* p, i32x4* a) {
    asm volatile(
        "global_load_dwordx4 %0, %8, off sc0 sc1\n\t"
        "global_load_dwordx4 %1, %8, off offset:16 sc0 sc1\n\t"
        "global_load_dwordx4 %2, %8, off offset:128 sc0 sc1\n\t"
        "global_load_dwordx4 %3, %8, off offset:144 sc0 sc1\n\t"
        "global_load_dwordx4 %4, %8, off offset:256 sc0 sc1\n\t"
        "global_load_dwordx4 %5, %8, off offset:272 sc0 sc1\n\t"
        "global_load_dwordx4 %6, %8, off offset:384 sc0 sc1\n\t"
        "global_load_dwordx4 %7, %8, off offset:400 sc0 sc1"
        : "=&v"(a[0]), "=&v"(a[1]), "=&v"(a[2]), "=&v"(a[3]),
          "=&v"(a[4]), "=&v"(a[5]), "=&v"(a[6]), "=&v"(a[7])
        : "v"(p)
        : "memory");
}
#define AWAIT8(a) \
    asm volatile("s_waitcnt vmcnt(0)" \
        : "+v"(a[0]), "+v"(a[1]), "+v"(a[2]), "+v"(a[3]), \
          "+v"(a[4]), "+v"(a[5]), "+v"(a[6]), "+v"(a[7]) :: "memory")

// Fire-and-forget tagged h stores (dword = tag<<16 | bf16). Base points at
// row rowbase+2 so the 4 row-stride-2048B offsets fit the signed-13-bit imm.
__device__ __forceinline__ void store_h4d(void* p, uint32_t d0, uint32_t d1,
                                          uint32_t d2, uint32_t d3) {
    asm volatile(
        "global_store_dword %4, %0, off offset:-4096 sc0 sc1\n\t"
        "global_store_dword %4, %1, off offset:-2048 sc0 sc1\n\t"
        "global_store_dword %4, %2, off sc0 sc1\n\t"
        "global_store_dword %4, %3, off offset:2048 sc0 sc1"
        :: "v"(d0), "v"(d1), "v"(d2), "v"(d3), "v"(p)
        : "memory");
}

__global__ void __launch_bounds__(256, 1)
lstm_kernel(const float* __restrict__ values, const float* __restrict__ masks,
            const float* __restrict__ Wih_f, const float* __restrict__ Whh_f,
            const float* __restrict__ bih_f, const float* __restrict__ bhh_f,
            const float* __restrict__ Wih_b, const float* __restrict__ Whh_b,
            const float* __restrict__ bih_b, const float* __restrict__ bhh_b,
            const float* __restrict__ W_imp, const float* __restrict__ b_imp,
            uint32_t* h_buf, float* hfin)
{
    extern __shared__ char smem_raw[];
    short*    imp_lds = (short*)smem_raw;
    uint32_t* xm_lds  = (uint32_t*)(smem_raw + 16384);
    char*     aP      = smem_raw + 49216;

    const int tid  = threadIdx.x;
    const int lane = tid & 63;
    const int nw   = tid >> 6;                 // wave 0..3 ; owns chunks nw*4..nw*4+3

    // 256 wgs = 2 dirs x 16 batch-groups x 8 col-wgs (64 cols each)
    const int bid = blockIdx.x;
    const int g   = bid & 15;                  // batch group (rows g*16..+15)
    const int w   = (bid >> 4) & 7;            // col-wg (owns hcols w*64..+63)
    const int d   = bid >> 7;                  // direction

    const float* Whh = d ? Whh_b : Whh_f;
    const float* Wih = d ? Wih_b : Wih_f;
    const float* bih = d ? bih_b : bih_f;
    const float* bhh = d ? bhh_b : bhh_f;

    const int col16 = lane & 15;
    const int koff4 = lane >> 4;                      // 0..3
    const int jcol  = w * 64 + nw * 16 + col16;       // owned h-column
    const int swz   = (col16 & 7) << 4;               // LDS XOR-swizzle (16B slots)

    // ---- stage W_imp B-tile into LDS, replicated across all 16 cols ----
    for (int c = tid; c < 1024; c += 256) {
        int ckoff = (c >> 4) & 3, ckb = c >> 6;
        int k0 = ckb * 32 + ckoff * 8;
        short* dst = &imp_lds[c * 8];
        #pragma unroll
        for (int j = 0; j < 8; ++j) dst[j] = f2bf(W_imp[k0 + j]);
    }
    // ---- stage packed (x*(1-m), m) bf16 pairs for this wg's 16 batch rows ----
    for (int i = tid; i < 16 * 512; i += 256) {
        int r = i >> 9, s = i & 511;
        float x = values[(g * 16 + r) * S_ + s];
        float m = masks[(g * 16 + r) * S_ + s];
        float a = x * (1.0f - m);
        xm_lds[r * XM_STRIDE + s] =
            (uint32_t)(uint16_t)f2bf(a) | ((uint32_t)(uint16_t)f2bf(m) << 16);
    }

    // ---- B fragments (4 gate tiles) in registers: 256 regs, static over all steps ----
    s16x8 bfr[4][16];
    {
        const float* base = Whh + (size_t)jcol * 512 + koff4 * 8;
        #pragma unroll
        for (int gg = 0; gg < 4; ++gg) {
            const float* src = base + (size_t)gg * 512 * 512;
            #pragma unroll
            for (int kb = 0; kb < 16; ++kb) {
                f32x4 v0 = *(const f32x4*)(src + kb * 32);
                f32x4 v1 = *(const f32x4*)(src + kb * 32 + 4);
                s16x8 b;
                b[0] = f2bf(v0[0]); b[1] = f2bf(v0[1]); b[2] = f2bf(v0[2]); b[3] = f2bf(v0[3]);
                b[4] = f2bf(v1[0]); b[5] = f2bf(v1[1]); b[6] = f2bf(v1[2]); b[7] = f2bf(v1[3]);
                bfr[gg][kb] = b;
            }
        }
    }

    float bias[4], wih[4];
    #pragma unroll
    for (int gg = 0; gg < 4; ++gg) {
        int gc = gg * 512 + jcol;
        bias[gg] = bih[gc] + bhh[gc];
        wih[gg]  = Wih[gc];
    }
    const float bimp  = b_imp[0];
    const float start = d ? -128.0f : 128.0f;

    const int arow    = g * 16 + col16;           // A row this lane loads (abs batch)
    const int rowloc  = koff4 * 4;                // first local C-row of this lane
    const int rowbase = g * 16 + rowloc;          // abs
    const int imp_off = (koff4 * 16 + col16) * 8; // lds chunk offset within a kb block

    // ---- init cell: h0,c0 = lstm_cell(start, 0, 0); tagged store (tag=1) ----
    float c_reg[4];
    {
        float pre[4];
        #pragma unroll
        for (int gg = 0; gg < 4; ++gg) pre[gg] = start * wih[gg] + bias[gg];
        float i0 = sig_(pre[0]), g0 = tanh_(pre[2]), o0 = sig_(pre[3]);
        float c0 = i0 * g0;
        float h0 = o0 * tanh_(c0);
        #pragma unroll
        for (int r = 0; r < 4; ++r) c_reg[r] = c0;
        uint32_t dwi = (1u << 16) | (uint32_t)(unsigned short)(unsigned)f2bf(h0);
        uint32_t* dst = h_buf + (size_t)d * (B_ * H_)            // parity-0 buffer
                        + (size_t)(rowbase + 2) * H_ + jcol;
        store_h4d(dst, dwi, dwi, dwi, dwi);   // fire-and-forget; tags gate readers
    }

    __syncthreads();   // LDS staging complete (4 waves)

    // ---- sequential scan ----
    for (int t = 0; t < S_; ++t) {
        const int p = t & 1;
        const uint32_t* hb_r = h_buf + (size_t)p       * (2 * B_ * H_) + (size_t)d * (B_ * H_);
        uint32_t*       hb_w = h_buf + (size_t)(p ^ 1) * (2 * B_ * H_) + (size_t)d * (B_ * H_);

        // ---- stage 1: poll this wave's 4 owned chunks (fused flag+data) ----
        // Accept iff every dword's high-16 tag >= t+1. Monotone tags + parity
        // double-buffer make ">=" safe: a tag t+3 cannot appear in this buffer
        // until every group wg (incl. this one) finished consuming tag t+1.
        const uint32_t tgtv = (uint32_t)(t + 1) << 16;
        const uint32_t* ap = hb_r + (size_t)arow * H_ + nw * 128 + koff4 * 8;
        i32x4 araw[8];
        load_a8_issue(ap, araw);
        for (;;) {
            AWAIT8(araw);
            uint32_t mn = 0xffffffffu;
            #pragma unroll
            for (int j = 0; j < 8; ++j) {
                uint32_t u0 = (uint32_t)araw[j][0], u1 = (uint32_t)araw[j][1];
                uint32_t u2 = (uint32_t)araw[j][2], u3 = (uint32_t)araw[j][3];
                uint32_t m0 = u0 < u1 ? u0 : u1;
                uint32_t m1 = u2 < u3 ? u2 : u3;
                uint32_t mm = m0 < m1 ? m0 : m1;
                mn = mn < mm ? mn : mm;
            }
            if (__ballot(mn >= tgtv) == ~0ull) break;
            __builtin_amdgcn_s_sleep(2);
            load_a8_issue(ap, araw);
        }

        // ---- stage 2: perm-pack to bf16, ds_write own chunks (swizzled) ----
        {
            char* wb = aP + p * 16384 + col16 * 1024;
            #pragma unroll
            for (int j = 0; j < 4; ++j) {
                i32x4 pk;
                pk[0] = (int)pklo((uint32_t)araw[2*j  ][1], (uint32_t)araw[2*j  ][0]);
                pk[1] = (int)pklo((uint32_t)araw[2*j  ][3], (uint32_t)araw[2*j  ][2]);
                pk[2] = (int)pklo((uint32_t)araw[2*j+1][1], (uint32_t)araw[2*j+1][0]);
                pk[3] = (int)pklo((uint32_t)araw[2*j+1][3], (uint32_t)araw[2*j+1][2]);
                int boff = (((nw * 4 + j) * 64 + koff4 * 16) ^ swz);
                *(i32x4*)(wb + boff) = pk;
            }
        }
        __syncthreads();   // all 16 chunks of h_t now in LDS parity p

        // ---- stage 3: MFMA over full K from LDS ----
        f32x4 acc0 = {0,0,0,0}, acc1 = {0,0,0,0}, acc2 = {0,0,0,0}, acc3 = {0,0,0,0};
        f32x4 acc4 = {0,0,0,0};   // imp (W_imp replicated => valid in every lane)
        const char* rb = aP + p * 16384 + col16 * 1024;
        #pragma unroll
        for (int kb = 0; kb < 16; ++kb) {
            s16x8 a = *(const s16x8*)(rb + ((kb * 64 + koff4 * 16) ^ swz));
            acc0 = __builtin_amdgcn_mfma_f32_16x16x32_bf16(a, bfr[0][kb], acc0, 0, 0, 0);
            acc1 = __builtin_amdgcn_mfma_f32_16x16x32_bf16(a, bfr[1][kb], acc1, 0, 0, 0);
            acc2 = __builtin_amdgcn_mfma_f32_16x16x32_bf16(a, bfr[2][kb], acc2, 0, 0, 0);
            acc3 = __builtin_amdgcn_mfma_f32_16x16x32_bf16(a, bfr[3][kb], acc3, 0, 0, 0);
            s16x8 b4 = *(const s16x8*)&imp_lds[kb * 512 + imp_off];
            acc4 = __builtin_amdgcn_mfma_f32_16x16x32_bf16(a, b4, acc4, 0, 0, 0);
        }

        // ---- stage 4: per-lane cc + gates -> c,h ; tagged fire-and-forget store ----
        const uint32_t tagw = (uint32_t)(t + 2) << 16;
        uint32_t dw[4];
        #pragma unroll
        for (int r = 0; r < 4; ++r) {
            uint32_t pk = xm_lds[(rowloc + r) * XM_STRIDE + t];
            float cc = bflo(pk) + bfhi(pk) * (acc4[r] + bimp);
            float pi = acc0[r] + cc * wih[0] + bias[0];
            float pf = acc1[r] + cc * wih[1] + bias[1];
            float pg = acc2[r] + cc * wih[2] + bias[2];
            float po = acc3[r] + cc * wih[3] + bias[3];
            float iv = sig_(pi), fv = sig_(pf), gv = tanh_(pg), ov = sig_(po);
            c_reg[r] = fv * c_reg[r] + iv * gv;
            float hn = ov * tanh_(c_reg[r]);
            dw[r] = tagw | (uint32_t)(unsigned short)(unsigned)f2bf(hn);
            if (t == S_ - 1) hfin[d * (B_ * H_) + (rowbase + r) * H_ + jcol] = hn;
        }
        store_h4d(hb_w + (size_t)(rowbase + 2) * H_ + jcol, dw[0], dw[1], dw[2], dw[3]);
        // no drain, no flag, no post-store barrier: per-dword tags carry readiness
    }
}

__global__ void __launch_bounds__(256)
epilogue_kernel(const float* __restrict__ values, const float* __restrict__ masks,
                const float* __restrict__ hfin, float* __restrict__ out)
{
    int i = blockIdx.x * 256 + threadIdx.x;          // 0..131071
    // hfin aliases out (same buffer): per-thread read-before-write of the
    // exact same two elements, so aliasing is safe.
    float h = hfin[i] + hfin[B_ * H_ + i];           // h_f + h_b
    float xv = values[i], mv = masks[i];
    float blend = h * (1.0f - mv) + xv * mv;
    out[i] = h;                                      // output 0: h (B,H)
    out[B_ * H_ + i] = blend;                        // output 1: out (B,S,1)
}

extern "C" void kernel_launch(void* const* d_in, const int* in_sizes, int n_in,
                              void* d_out, int out_size, void* d_ws, size_t ws_size,
                              hipStream_t stream) {
    const float* values = (const float*)d_in[0];
    const float* masks  = (const float*)d_in[1];
    const float* Wih_f  = (const float*)d_in[2];
    const float* Whh_f  = (const float*)d_in[3];
    const float* bih_f  = (const float*)d_in[4];
    const float* bhh_f  = (const float*)d_in[5];
    const float* Wih_b  = (const float*)d_in[6];
    const float* Whh_b  = (const float*)d_in[7];
    const float* bih_b  = (const float*)d_in[8];
    const float* bhh_b  = (const float*)d_in[9];
    const float* W_imp  = (const float*)d_in[10];
    const float* b_imp  = (const float*)d_in[11];

    // ws layout: [0, 2MB) tagged h_buf (2 parities x 2 dirs x 256x512 dwords).
    // hfin ALIASES d_out (2 dirs x 256x512 f32 = out_size): keeps d_ws usage
    // at exactly 2 MB, inside the proven workspace envelope.
    uint32_t* h_buf = (uint32_t*)d_ws;
    float*    hfin  = (float*)d_out;

    // zero ALL tags each launch (stale tags from a prior launch would false-pass)
    hipMemsetAsync(d_ws, 0, (size_t)2 * 2 * B_ * H_ * 4, stream);

    hipFuncSetAttribute((const void*)lstm_kernel,
                        hipFuncAttributeMaxDynamicSharedMemorySize, LDS_BYTES);

    void* args[] = {
        (void*)&values, (void*)&masks,
        (void*)&Wih_f, (void*)&Whh_f, (void*)&bih_f, (void*)&bhh_f,
        (void*)&Wih_b, (void*)&Whh_b, (void*)&bih_b, (void*)&bhh_b,
        (void*)&W_imp, (void*)&b_imp,
        (void*)&h_buf, (void*)&hfin
    };
    hipError_t err = hipLaunchCooperativeKernel((const void*)lstm_kernel,
                                                dim3(256), dim3(256), args,
                                                (unsigned int)LDS_BYTES, stream);
    if (err != hipSuccess) {
        lstm_kernel<<<dim3(256), dim3(256), LDS_BYTES, stream>>>(
            values, masks, Wih_f, Whh_f, bih_f, bhh_f,
            Wih_b, Whh_b, bih_b, bhh_b, W_imp, b_imp, h_buf, hfin);
    }

    epilogue_kernel<<<dim3((B_ * H_) / 256), dim3(256), 0, stream>>>(
        values, masks, hfin, (float*)d_out);
}